// Round 6
// baseline (135.149 us; speedup 1.0000x reference)
//
#include <hip/hip_runtime.h>

// AQLM dequant: codes [8192,1024,2] i32, codebooks [2,65536,1,8] f32,
// scales [8192,1,1,1] f32 -> out [8192,8192] f32.
// out[o, i*8+j] = (cb0[codes[o,i,0]][j] + cb1[codes[o,i,1]][j]) * scales[o]
//
// Round 6: store-path fix. Theory: nt stores bypassed L2 write-combining and
// R5's 32B-stride store pattern wrote half-lines -> effective write BW ~2 TB/s
// dominated every round. Now: slot-indexed (lanes store consecutive 16B,
// fully coalesced like the 6.9 TB/s fill kernel) with PLAIN stores. Gather:
// bf16 codebooks in d_ws (2 MiB), each lane loads its 8B half-entry (lane
// pairs adjacent in a line). Codes stay nontemporal (read-once).

#define O_GROUPS 8192
#define I_GROUPS 1024
#define CB_SIZE  65536
#define BATCH    4

typedef float          f32x4 __attribute__((ext_vector_type(4)));
typedef int            i32x2 __attribute__((ext_vector_type(2)));
typedef unsigned short u16x4 __attribute__((ext_vector_type(4)));

__device__ __forceinline__ unsigned short f2bf(float f) {
    unsigned int u = __float_as_uint(f);
    u += 0x7FFF + ((u >> 16) & 1);          // round-to-nearest-even
    return (unsigned short)(u >> 16);
}
__device__ __forceinline__ float bf2f(unsigned short h) {
    return __uint_as_float((unsigned int)h << 16);
}

// pre-pass: codebooks f32 [2*65536*8] -> bf16 in d_ws (~4 us)
__global__ __launch_bounds__(256) void cb_convert_kernel(
    const f32x4* __restrict__ cb, u16x4* __restrict__ cbh)
{
    const int i = blockIdx.x * 256 + threadIdx.x;   // 262144 threads, 4 floats each
    f32x4 v = cb[i];
    u16x4 h;
    h.x = f2bf(v.x); h.y = f2bf(v.y); h.z = f2bf(v.z); h.w = f2bf(v.w);
    cbh[i] = h;
}

__global__ __launch_bounds__(256) void aqlm_dequant_bf16_kernel(
    const i32x2* __restrict__ codes,   // [O*I] code pairs
    const u16x4* __restrict__ cbh,     // [2*CB_SIZE*2] bf16 half-entries, 8B each
    const float* __restrict__ scales,  // [O]
    f32x4*       __restrict__ out)     // [O*I*2]  slot-indexed, 16B per slot
{
    const int tid  = threadIdx.x;
    const int base = blockIdx.x * (256 * BATCH) + tid;  // slot idx, coalesced per k

    int   slot[BATCH];
    i32x2 c[BATCH];
    #pragma unroll
    for (int k = 0; k < BATCH; ++k) {
        slot[k] = base + k * 256;
        c[k] = __builtin_nontemporal_load(&codes[slot[k] >> 1]);  // pair shares 8B
    }

    u16x4 a[BATCH], b[BATCH];
    #pragma unroll
    for (int k = 0; k < BATCH; ++k) {
        const int h = slot[k] & 1;                       // which 8B half-entry
        a[k] = cbh[(size_t)c[k].x * 2 + h];              // codebook 0
        b[k] = cbh[((size_t)CB_SIZE + c[k].y) * 2 + h];  // codebook 1
    }

    #pragma unroll
    for (int k = 0; k < BATCH; ++k) {
        const float s = scales[slot[k] >> 11];           // o = slot >> 11
        f32x4 r;
        r.x = (bf2f(a[k].x) + bf2f(b[k].x)) * s;
        r.y = (bf2f(a[k].y) + bf2f(b[k].y)) * s;
        r.z = (bf2f(a[k].z) + bf2f(b[k].z)) * s;
        r.w = (bf2f(a[k].w) + bf2f(b[k].w)) * s;
        out[slot[k]] = r;                                // plain coalesced store
    }
}

// fp32 fallback if ws_size can't hold the bf16 codebooks
__global__ __launch_bounds__(256) void aqlm_dequant_f32_kernel(
    const i32x2* __restrict__ codes,
    const f32x4* __restrict__ cb,
    const float* __restrict__ scales,
    f32x4*       __restrict__ out)
{
    const int tid  = threadIdx.x;
    const int base = blockIdx.x * (256 * BATCH) + tid;
    int   slot[BATCH];
    i32x2 c[BATCH];
    #pragma unroll
    for (int k = 0; k < BATCH; ++k) {
        slot[k] = base + k * 256;
        c[k] = __builtin_nontemporal_load(&codes[slot[k] >> 1]);
    }
    f32x4 a[BATCH], b[BATCH];
    #pragma unroll
    for (int k = 0; k < BATCH; ++k) {
        const int h = slot[k] & 1;
        a[k] = cb[(size_t)c[k].x * 2 + h];
        b[k] = cb[((size_t)CB_SIZE + c[k].y) * 2 + h];
    }
    #pragma unroll
    for (int k = 0; k < BATCH; ++k) {
        const float s = scales[slot[k] >> 11];
        f32x4 r = (a[k] + b[k]) * s;
        out[slot[k]] = r;
    }
}

extern "C" void kernel_launch(void* const* d_in, const int* in_sizes, int n_in,
                              void* d_out, int out_size, void* d_ws, size_t ws_size,
                              hipStream_t stream) {
    const i32x2* codes  = (const i32x2*)d_in[0];
    const float* scales = (const float*)d_in[2];
    f32x4*       out    = (f32x4*)d_out;

    const size_t cbh_bytes = (size_t)2 * CB_SIZE * 8 * 2;   // 2 MiB
    const int total_slots = O_GROUPS * I_GROUPS * 2;        // 16777216
    const int grid = total_slots / (256 * BATCH);           // 16384, exact
    if (ws_size >= cbh_bytes) {
        cb_convert_kernel<<<1024, 256, 0, stream>>>((const f32x4*)d_in[1],
                                                    (u16x4*)d_ws);
        aqlm_dequant_bf16_kernel<<<grid, 256, 0, stream>>>(
            codes, (const u16x4*)d_ws, scales, out);
    } else {
        aqlm_dequant_f32_kernel<<<grid, 256, 0, stream>>>(
            codes, (const f32x4*)d_in[1], scales, out);
    }
}